// Round 13
// baseline (4027.571 us; speedup 1.0000x reference)
//
#include <hip/hip_runtime.h>
#include <stdint.h>

#define M_DIM 8192
#define N_DIM 11008
#define K_DIM 4096

#define BM 256
#define BN 256
#define BK 64                    // i8: 64 B per row per tile
#define NT (K_DIM / BK)          // 64 K-tiles
#define GRID_M (M_DIM / BM)      // 32
#define GRID_N (N_DIM / BN)      // 43
#define NWG (GRID_M * GRID_N)    // 1376 (divisible by 8)

#define BUF (BM * BK)            // 16384 B per tile-buffer per matrix
#define NRING 5                  // ring-5: LDS = 5*2*16384 = 163840 B (160 KiB)

typedef int i32x4 __attribute__((ext_vector_type(4)));

__device__ __forceinline__ void gload16(const int8_t* src, int8_t* dst) {
    __builtin_amdgcn_global_load_lds(
        (const __attribute__((address_space(1))) uint32_t*)src,
        (__attribute__((address_space(3))) uint32_t*)dst, 16, 0, 0);
}

// ---------- pre-pass 1: per-row (token) absmax quant of x -> i8 + inv scale ----------

__global__ __launch_bounds__(256) void quant_x_kernel(
    const float* __restrict__ x, int8_t* __restrict__ xq, float* __restrict__ sinv)
{
    const int wave = blockIdx.x * 4 + (threadIdx.x >> 6);
    const int lane = threadIdx.x & 63;
    const float* row = x + (size_t)wave * K_DIM;

    float4 v[16];
    float mx = 0.0f;
    #pragma unroll
    for (int j = 0; j < 16; ++j) {
        v[j] = *(const float4*)(row + (j * 64 + lane) * 4);
        mx = fmaxf(mx, fmaxf(fmaxf(fabsf(v[j].x), fabsf(v[j].y)),
                             fmaxf(fabsf(v[j].z), fabsf(v[j].w))));
    }
    #pragma unroll
    for (int off = 32; off > 0; off >>= 1)
        mx = fmaxf(mx, __shfl_xor(mx, off));
    if (mx < 1e-30f) mx = 1e-30f;
    const float s = 127.0f / mx;

    int8_t* orow = xq + (size_t)wave * K_DIM;
    #pragma unroll
    for (int j = 0; j < 16; ++j) {
        int a = (int)__builtin_rintf(v[j].x * s);
        int b = (int)__builtin_rintf(v[j].y * s);
        int c = (int)__builtin_rintf(v[j].z * s);
        int d = (int)__builtin_rintf(v[j].w * s);
        uint32_t p = (uint32_t)(a & 0xFF) | ((uint32_t)(b & 0xFF) << 8) |
                     ((uint32_t)(c & 0xFF) << 16) | ((uint32_t)(d & 0xFF) << 24);
        *(uint32_t*)(orow + (j * 64 + lane) * 4) = p;
    }
    if (lane == 0) sinv[wave] = mx / 127.0f;
}

// ---------- pre-pass 2: f32 w -> sign(w) in i8 (exact {-1,0,+1}) ----------

__global__ __launch_bounds__(256) void sign_w_kernel(
    const float* __restrict__ w, int8_t* __restrict__ wq, long long n16)
{
    long long i = (long long)blockIdx.x * blockDim.x + threadIdx.x;
    const long long stride = (long long)gridDim.x * blockDim.x;
    for (; i < n16; i += stride) {
        const float* src = w + i * 16;
        uint32_t pk[4];
        #pragma unroll
        for (int q = 0; q < 4; ++q) {
            float4 f = *(const float4*)(src + q * 4);
            int a = (f.x > 0.f) ? 1 : ((f.x < 0.f) ? -1 : 0);
            int b = (f.y > 0.f) ? 1 : ((f.y < 0.f) ? -1 : 0);
            int c = (f.z > 0.f) ? 1 : ((f.z < 0.f) ? -1 : 0);
            int d = (f.w > 0.f) ? 1 : ((f.w < 0.f) ? -1 : 0);
            pk[q] = (uint32_t)(a & 0xFF) | ((uint32_t)(b & 0xFF) << 8) |
                    ((uint32_t)(c & 0xFF) << 16) | ((uint32_t)(d & 0xFF) << 24);
        }
        *(i32x4*)(wq + i * 16) = (i32x4){(int)pk[0], (int)pk[1], (int)pk[2], (int)pk[3]};
    }
}

// ---------- main GEMM (i8): 256x256, BK=64, 8 waves, RING-5 LDS (160 KiB),
// WAVE-PARITY ANTI-PHASE (r12 post-mortem): B-direct refuted (latency-bound);
// reverted to r11 A+B-in-LDS. r6-r11 showed per-tile = DS-leg + MFMA-leg
// SERIAL (2500 cy) under barrier-lockstep: both waves of a SIMD run the same
// body order (read-then-MFMA) so the DS and MFMA pipes alternate. Fix: waves
// wid and wid+4 share a SIMD (wid%4); wm=wid>>2 splits the pair. Body(t):
//   wm==0: reads(t+1) ; MFMA(t)
//   wm==1: MFMA(t) ; reads(t+1)
// -> each SIMD has one wave on the matrix pipe while its partner is on the DS
// pipe, swapping mid-body (m114: different-pipe waves co-schedule fully).
// Stage(t+4) issues at a uniform end-of-body point (vmcnt count preserved).
//
// Hazards (re-audited for both orders):
//  RAW stage(t+1)->reads(t+1): certified at boundary(t-1) (vmcnt ladder).
//  reads(t+1)->MFMA(t+1): compiler lgkm wait (plain C++ loads).
//  WAR slot tau: wave's reads(tau) complete before its MFMA(tau) issues ->
//   before boundary(tau); writer stage(tau+5) issues after boundary(tau). OK
//   for both parities (odd waves' reads(tau) happened in body(tau-1) too).
//  vmcnt ladder at boundary(t): outstanding = stage(t+3)x4 + stage(t+4)x4 ->
//   vmcnt(8) certifies stage(t+2); tail t==NT-4 -> vmcnt(4); else vmcnt(0).

__global__ __launch_bounds__(512, 2) void ternary_gemm_i8(
    const int8_t* __restrict__ A, const int8_t* __restrict__ B,
    const float* __restrict__ bias, const float* __restrict__ sinv,
    float* __restrict__ out)
{
    extern __shared__ int8_t lds[];
    int8_t* As = lds;                   // [NRING][BUF]
    int8_t* Bs = lds + NRING * BUF;     // [NRING][BUF]

    const int tid  = threadIdx.x;
    const int lane = tid & 63;
    const int wid  = tid >> 6;        // 0..7
    const int wm   = wid >> 2;        // 0..1  (SIMD-pair parity AND M-half)
    const int wn   = wid & 3;         // 0..3
    const int l15  = lane & 15;
    const int l4   = lane >> 4;       // 0..3

    // T1: bijective XCD swizzle (NWG % 8 == 0), bn-minor for A-panel L2 reuse
    const int bid = blockIdx.x;
    const int swz = (bid & 7) * (NWG / 8) + (bid >> 3);
    const int bm  = swz / GRID_N;
    const int bn  = swz % GRID_N;
    const long brow = (long)bm * BM;
    const long bcol = (long)bn * BN;

    // ---- staging addressing (r6-verified): inst r covers rows r*128+(tid>>2),
    // 16B-slot tid&3; LDS dest linear; global src slot inverse-swizzled ----
    const int rowt = tid >> 2;                        // 0..127
    const int ssrc = (tid & 3) ^ ((tid >> 3) & 3);
    const int8_t* pA = A + (size_t)(brow + rowt) * K_DIM + ssrc * 16;
    const int8_t* pB = B + (size_t)(bcol + rowt) * K_DIM + ssrc * 16;

    auto stageA2 = [&](int t, int bslot) {
        #pragma unroll
        for (int r = 0; r < 2; ++r)
            gload16(pA + (size_t)r * 128 * K_DIM + (size_t)t * BK,
                    As + bslot * BUF + r * 8192 + wid * 1024 + (lane << 4));
    };
    auto stageB2 = [&](int t, int bslot) {
        #pragma unroll
        for (int r = 0; r < 2; ++r)
            gload16(pB + (size_t)r * 128 * K_DIM + (size_t)t * BK,
                    Bs + bslot * BUF + r * 8192 + wid * 1024 + (lane << 4));
    };

    // ---- fragment read addressing (r6-verified swizzle) ----
    const int slot = l4 ^ ((l15 >> 1) & 3);
    const int aOff = (wm * 16 + l15) * 64 + slot * 16;   // + m*2048
    const int bOff = (wn * 16 + l15) * 64 + slot * 16;   // + n*4096

    i32x4 acc[8][4];
    #pragma unroll
    for (int m = 0; m < 8; ++m)
        #pragma unroll
        for (int n = 0; n < 4; ++n) acc[m][n] = (i32x4){0, 0, 0, 0};

    i32x4 arA[8], brA[4], arB[8], brB[4];

    auto readFragsS = [&](int s, i32x4 (&ar)[8], i32x4 (&br)[4]) {
        const int8_t* Ab = As + s * BUF;
        const int8_t* Bb = Bs + s * BUF;
        #pragma unroll
        for (int n = 0; n < 4; ++n) br[n] = *(const i32x4*)(Bb + n * 4096 + bOff);
        #pragma unroll
        for (int m = 0; m < 8; ++m) ar[m] = *(const i32x4*)(Ab + m * 2048 + aOff);
    };

    // ---- prologue: stage tiles 0..3; drain 0,1 (vmcnt(8)); barrier; frags(0) ----
    stageA2(0, 0); stageB2(0, 0);
    stageA2(1, 1); stageB2(1, 1);
    stageA2(2, 2); stageB2(2, 2);
    stageA2(3, 3); stageB2(3, 3);
    asm volatile("s_waitcnt vmcnt(8)" ::: "memory");
    __builtin_amdgcn_s_barrier();
    __builtin_amdgcn_sched_barrier(0);
    readFragsS(0, arA, brA);
    __builtin_amdgcn_sched_barrier(0);

    int sn = 1;   // ring slot of tile t+1 (reads)
    int ss = 4;   // ring slot of tile t+4 (stage)

    auto mfma32 = [&](i32x4 (&arc)[8], i32x4 (&brc)[4]) {
        __builtin_amdgcn_s_setprio(1);
        #pragma unroll
        for (int m = 0; m < 8; ++m)
            #pragma unroll
            for (int n = 0; n < 4; ++n)
                acc[m][n] = __builtin_amdgcn_mfma_i32_16x16x64_i8(arc[m], brc[n], acc[m][n], 0, 0, 0);
        __builtin_amdgcn_s_setprio(0);
    };

    auto body = [&](int t, i32x4 (&arc)[8], i32x4 (&brc)[4],
                           i32x4 (&arn)[8], i32x4 (&brn)[4]) {
        const bool rd = (t + 1 < NT);
        const bool st = (t + 4 < NT);

        if (wm == 0) {
            // DS phase first, MFMA second
            if (rd) readFragsS(sn, arn, brn);
            __builtin_amdgcn_sched_barrier(0);
            mfma32(arc, brc);
        } else {
            // MFMA first, DS phase second (anti-phase partner)
            mfma32(arc, brc);
            __builtin_amdgcn_sched_barrier(0);
            if (rd) readFragsS(sn, arn, brn);
        }
        __builtin_amdgcn_sched_barrier(0);

        // uniform stage point (vmcnt count identical across parities)
        if (st) { stageA2(t + 4, ss); stageB2(t + 4, ss); }
        __builtin_amdgcn_sched_barrier(0);

        // ---- tile boundary: vmcnt ladder + barrier ----
        if (t <= NT - 5)      { asm volatile("s_waitcnt vmcnt(8)" ::: "memory"); }
        else if (t == NT - 4) { asm volatile("s_waitcnt vmcnt(4)" ::: "memory"); }
        else                  { asm volatile("s_waitcnt vmcnt(0)" ::: "memory"); }
        __builtin_amdgcn_s_barrier();
        __builtin_amdgcn_sched_barrier(0);

        sn = (sn == NRING - 1) ? 0 : sn + 1;
        ss = (ss == NRING - 1) ? 0 : ss + 1;
    };

    for (int t = 0; t < NT; t += 2) {
        body(t,     arA, brA, arB, brB);
        body(t + 1, arB, brB, arA, brA);
    }

    // ---- epilogue: out = acc * sinv[row] + bias[col] ----
    // C/D layout (dtype-independent, m121-128): col=lane&15, row=(lane>>4)*4+reg
    int   cols[4];
    float bv[4];
    #pragma unroll
    for (int n = 0; n < 4; ++n) {
        cols[n] = (int)bcol + n * 64 + wn * 16 + l15;
        bv[n] = bias[cols[n]];
    }
    #pragma unroll
    for (int m = 0; m < 8; ++m) {
        const size_t row0 = (size_t)brow + m * 32 + wm * 16 + l4 * 4;
        float s0 = sinv[row0], s1 = sinv[row0 + 1], s2 = sinv[row0 + 2], s3 = sinv[row0 + 3];
        #pragma unroll
        for (int n = 0; n < 4; ++n) {
            out[(row0 + 0) * N_DIM + cols[n]] = (float)acc[m][n][0] * s0 + bv[n];
            out[(row0 + 1) * N_DIM + cols[n]] = (float)acc[m][n][1] * s1 + bv[n];
            out[(row0 + 2) * N_DIM + cols[n]] = (float)acc[m][n][2] * s2 + bv[n];
            out[(row0 + 3) * N_DIM + cols[n]] = (float)acc[m][n][3] * s3 + bv[n];
        }
    }
}

// ---------- fallback (only if workspace too small): correct but slow ----------

__global__ void naive_kernel(const float* __restrict__ x, const float* __restrict__ w,
                             const float* __restrict__ bias, float* __restrict__ out) {
    long long o = (long long)blockIdx.x * blockDim.x + threadIdx.x;
    if (o >= (long long)M_DIM * N_DIM) return;
    int row = (int)(o / N_DIM), col = (int)(o % N_DIM);
    float s = 0.0f;
    const float* xr = x + (size_t)row * K_DIM;
    const float* wr = w + (size_t)col * K_DIM;
    for (int k = 0; k < K_DIM; ++k) {
        float wv = wr[k];
        s += (wv > 0.0f) ? xr[k] : ((wv < 0.0f) ? -xr[k] : 0.0f);
    }
    out[o] = s + bias[col];
}

// ---------- launch ----------

extern "C" void kernel_launch(void* const* d_in, const int* in_sizes, int n_in,
                              void* d_out, int out_size, void* d_ws, size_t ws_size,
                              hipStream_t stream) {
    const float* x    = (const float*)d_in[0];
    const float* w    = (const float*)d_in[1];
    const float* bias = (const float*)d_in[2];
    float* out        = (float*)d_out;

    const size_t xq_bytes = (size_t)M_DIM * K_DIM;        // 33.6 MB
    const size_t wq_bytes = (size_t)N_DIM * K_DIM;        // 45.1 MB
    const size_t si_bytes = (size_t)M_DIM * sizeof(float);

    if (ws_size >= xq_bytes + wq_bytes + si_bytes) {
        int8_t* xq   = (int8_t*)d_ws;
        int8_t* wq   = (int8_t*)((char*)d_ws + xq_bytes);
        float*  sinv = (float*)((char*)d_ws + xq_bytes + wq_bytes);

        quant_x_kernel<<<M_DIM / 4, 256, 0, stream>>>(x, xq, sinv);
        const long long n16 = ((long long)N_DIM * K_DIM) / 16;
        sign_w_kernel<<<2048, 256, 0, stream>>>(w, wq, n16);

        const int lds_bytes = NRING * 2 * BUF;   // 163840
        hipFuncSetAttribute(reinterpret_cast<const void*>(ternary_gemm_i8),
                            hipFuncAttributeMaxDynamicSharedMemorySize, lds_bytes);
        ternary_gemm_i8<<<NWG, 512, lds_bytes, stream>>>(xq, wq, bias, sinv, out);
    } else {
        const long long total = (long long)M_DIM * N_DIM;
        naive_kernel<<<(int)((total + 255) / 256), 256, 0, stream>>>(x, w, bias, out);
    }
}

// Round 14
// 481.177 us; speedup vs baseline: 8.3703x; 8.3703x over previous
//
#include <hip/hip_runtime.h>
#include <stdint.h>

#define M_DIM 8192
#define N_DIM 11008
#define K_DIM 4096

#define BM 256
#define BN 256
#define BK 64                    // i8: 64 B per row per tile
#define NT (K_DIM / BK)          // 64 K-tiles
#define GRID_M (M_DIM / BM)      // 32
#define GRID_N (N_DIM / BN)      // 43
#define NWG (GRID_M * GRID_N)    // 1376 (divisible by 8)

#define BUF (BM * BK)            // 16384 B per tile-buffer per matrix
#define NRING 5                  // ring-5: LDS = 5*2*16384 = 163840 B (160 KiB)

typedef int i32x4 __attribute__((ext_vector_type(4)));

__device__ __forceinline__ void gload16(const int8_t* src, int8_t* dst) {
    __builtin_amdgcn_global_load_lds(
        (const __attribute__((address_space(1))) uint32_t*)src,
        (__attribute__((address_space(3))) uint32_t*)dst, 16, 0, 0);
}

// ---------- pre-pass 1: per-row (token) absmax quant of x -> i8 + inv scale ----------

__global__ __launch_bounds__(256) void quant_x_kernel(
    const float* __restrict__ x, int8_t* __restrict__ xq, float* __restrict__ sinv)
{
    const int wave = blockIdx.x * 4 + (threadIdx.x >> 6);
    const int lane = threadIdx.x & 63;
    const float* row = x + (size_t)wave * K_DIM;

    float4 v[16];
    float mx = 0.0f;
    #pragma unroll
    for (int j = 0; j < 16; ++j) {
        v[j] = *(const float4*)(row + (j * 64 + lane) * 4);
        mx = fmaxf(mx, fmaxf(fmaxf(fabsf(v[j].x), fabsf(v[j].y)),
                             fmaxf(fabsf(v[j].z), fabsf(v[j].w))));
    }
    #pragma unroll
    for (int off = 32; off > 0; off >>= 1)
        mx = fmaxf(mx, __shfl_xor(mx, off));
    if (mx < 1e-30f) mx = 1e-30f;
    const float s = 127.0f / mx;

    int8_t* orow = xq + (size_t)wave * K_DIM;
    #pragma unroll
    for (int j = 0; j < 16; ++j) {
        int a = (int)__builtin_rintf(v[j].x * s);
        int b = (int)__builtin_rintf(v[j].y * s);
        int c = (int)__builtin_rintf(v[j].z * s);
        int d = (int)__builtin_rintf(v[j].w * s);
        uint32_t p = (uint32_t)(a & 0xFF) | ((uint32_t)(b & 0xFF) << 8) |
                     ((uint32_t)(c & 0xFF) << 16) | ((uint32_t)(d & 0xFF) << 24);
        *(uint32_t*)(orow + (j * 64 + lane) * 4) = p;
    }
    if (lane == 0) sinv[wave] = mx / 127.0f;
}

// ---------- pre-pass 2: f32 w -> sign(w) in i8 (exact {-1,0,+1}) ----------

__global__ __launch_bounds__(256) void sign_w_kernel(
    const float* __restrict__ w, int8_t* __restrict__ wq, long long n16)
{
    long long i = (long long)blockIdx.x * blockDim.x + threadIdx.x;
    const long long stride = (long long)gridDim.x * blockDim.x;
    for (; i < n16; i += stride) {
        const float* src = w + i * 16;
        uint32_t pk[4];
        #pragma unroll
        for (int q = 0; q < 4; ++q) {
            float4 f = *(const float4*)(src + q * 4);
            int a = (f.x > 0.f) ? 1 : ((f.x < 0.f) ? -1 : 0);
            int b = (f.y > 0.f) ? 1 : ((f.y < 0.f) ? -1 : 0);
            int c = (f.z > 0.f) ? 1 : ((f.z < 0.f) ? -1 : 0);
            int d = (f.w > 0.f) ? 1 : ((f.w < 0.f) ? -1 : 0);
            pk[q] = (uint32_t)(a & 0xFF) | ((uint32_t)(b & 0xFF) << 8) |
                    ((uint32_t)(c & 0xFF) << 16) | ((uint32_t)(d & 0xFF) << 24);
        }
        *(i32x4*)(wq + i * 16) = (i32x4){(int)pk[0], (int)pk[1], (int)pk[2], (int)pk[3]};
    }
}

// ---------- main GEMM (i8): 256x256, BK=64, 8 waves, RING-5 LDS (160 KiB),
// WAVE-PARITY ANTI-PHASE, SPILL-PROOF (r13 post-mortem): the in-loop parity
// branch joined both arms' live ranges -> VGPR+AGPR > 256 -> acc spilled
// (WRITE_SIZE 9.4 GB). Fix: TWO SEPARATE TOP-LEVEL K-LOOPS selected by the
// wave-uniform, loop-invariant wm. Each arm register-allocates independently
// (r11 pressure: ~124 VGPR + 128 AGPR).
//
// Mechanism (r13 refined model): a wave issuing 12 back-to-back ds_read_b128
// stalls in its own issue stream when the DS queue fills; in lockstep both
// waves of a SIMD stall together (matrix pipe idle), then both MFMA (DS pipe
// idle) -> serial DS+MFMA sum (2500 cy/tile), invariant to intra-wave order.
// Anti-phase: evens [reads ; MFMA], odds [MFMA half ; reads ; MFMA half] ->
// each SIMD always has one wave feeding the matrix pipe while the partner
// occupies DS issue. Odds' reads sit mid-body so their consumers (next body's
// first MFMA half) have ~500 cy slack.
//
// Hazard invariants (identical across arms): per body exactly one s_barrier,
// stage(t+4) immediately before the boundary wait (per-wave vmcnt counts are
// arm-independent); RAW stage(t+1)->reads(t+1) certified at boundary(t-1)
// (vmcnt ladder 8/4/0); reads->MFMA by compiler lgkm (plain C++ loads); WAR
// slot tau: reads(tau) complete before that wave's boundary(tau), writer
// stage(tau+5) issues after it.

__global__ __launch_bounds__(512, 2) void ternary_gemm_i8(
    const int8_t* __restrict__ A, const int8_t* __restrict__ B,
    const float* __restrict__ bias, const float* __restrict__ sinv,
    float* __restrict__ out)
{
    extern __shared__ int8_t lds[];
    int8_t* As = lds;                   // [NRING][BUF]
    int8_t* Bs = lds + NRING * BUF;     // [NRING][BUF]

    const int tid  = threadIdx.x;
    const int lane = tid & 63;
    const int wid  = tid >> 6;        // 0..7
    const int wm   = wid >> 2;        // 0..1  (SIMD-pair parity AND M-half)
    const int wn   = wid & 3;         // 0..3
    const int l15  = lane & 15;
    const int l4   = lane >> 4;       // 0..3

    // T1: bijective XCD swizzle (NWG % 8 == 0), bn-minor for A-panel L2 reuse
    const int bid = blockIdx.x;
    const int swz = (bid & 7) * (NWG / 8) + (bid >> 3);
    const int bm  = swz / GRID_N;
    const int bn  = swz % GRID_N;
    const long brow = (long)bm * BM;
    const long bcol = (long)bn * BN;

    // ---- staging addressing (r6-verified) ----
    const int rowt = tid >> 2;                        // 0..127
    const int ssrc = (tid & 3) ^ ((tid >> 3) & 3);
    const int8_t* pA = A + (size_t)(brow + rowt) * K_DIM + ssrc * 16;
    const int8_t* pB = B + (size_t)(bcol + rowt) * K_DIM + ssrc * 16;

    auto stageAB = [&](int t, int bslot) {
        #pragma unroll
        for (int r = 0; r < 2; ++r)
            gload16(pA + (size_t)r * 128 * K_DIM + (size_t)t * BK,
                    As + bslot * BUF + r * 8192 + wid * 1024 + (lane << 4));
        #pragma unroll
        for (int r = 0; r < 2; ++r)
            gload16(pB + (size_t)r * 128 * K_DIM + (size_t)t * BK,
                    Bs + bslot * BUF + r * 8192 + wid * 1024 + (lane << 4));
    };

    // ---- fragment read addressing (r6-verified swizzle) ----
    const int slot = l4 ^ ((l15 >> 1) & 3);
    const int aOff = (wm * 16 + l15) * 64 + slot * 16;   // + m*2048
    const int bOff = (wn * 16 + l15) * 64 + slot * 16;   // + n*4096

    i32x4 acc[8][4];
    #pragma unroll
    for (int m = 0; m < 8; ++m)
        #pragma unroll
        for (int n = 0; n < 4; ++n) acc[m][n] = (i32x4){0, 0, 0, 0};

    i32x4 arA[8], brA[4], arB[8], brB[4];

    auto readFragsS = [&](int s, i32x4 (&ar)[8], i32x4 (&br)[4]) {
        const int8_t* Ab = As + s * BUF;
        const int8_t* Bb = Bs + s * BUF;
        #pragma unroll
        for (int n = 0; n < 4; ++n) br[n] = *(const i32x4*)(Bb + n * 4096 + bOff);
        #pragma unroll
        for (int m = 0; m < 8; ++m) ar[m] = *(const i32x4*)(Ab + m * 2048 + aOff);
    };

    auto mfmaHalf = [&](i32x4 (&arc)[8], i32x4 (&brc)[4], int m0, int m1) {
        __builtin_amdgcn_s_setprio(1);
        #pragma unroll
        for (int m = m0; m < m1; ++m)
            #pragma unroll
            for (int n = 0; n < 4; ++n)
                acc[m][n] = __builtin_amdgcn_mfma_i32_16x16x64_i8(arc[m], brc[n], acc[m][n], 0, 0, 0);
        __builtin_amdgcn_s_setprio(0);
    };

    // ---- prologue (common): stage tiles 0..3; vmcnt(8); barrier; frags(0) ----
    stageAB(0, 0); stageAB(1, 1); stageAB(2, 2); stageAB(3, 3);
    asm volatile("s_waitcnt vmcnt(8)" ::: "memory");
    __builtin_amdgcn_s_barrier();
    __builtin_amdgcn_sched_barrier(0);
    readFragsS(0, arA, brA);
    __builtin_amdgcn_sched_barrier(0);

    int sn = 1;   // ring slot of tile t+1 (reads)
    int ss = 4;   // ring slot of tile t+4 (stage)

    auto boundary = [&](int t) {
        if (t + 4 < NT) stageAB(t + 4, ss);
        __builtin_amdgcn_sched_barrier(0);
        if (t <= NT - 5)      { asm volatile("s_waitcnt vmcnt(8)" ::: "memory"); }
        else if (t == NT - 4) { asm volatile("s_waitcnt vmcnt(4)" ::: "memory"); }
        else                  { asm volatile("s_waitcnt vmcnt(0)" ::: "memory"); }
        __builtin_amdgcn_s_barrier();
        __builtin_amdgcn_sched_barrier(0);
        sn = (sn == NRING - 1) ? 0 : sn + 1;
        ss = (ss == NRING - 1) ? 0 : ss + 1;
    };

    if (wm == 0) {
        // ===== even arm: [reads(t+1) ; MFMA(t) x32] =====
        auto bodyE = [&](int t, i32x4 (&arc)[8], i32x4 (&brc)[4],
                                i32x4 (&arn)[8], i32x4 (&brn)[4]) {
            if (t + 1 < NT) readFragsS(sn, arn, brn);
            __builtin_amdgcn_sched_barrier(0);
            mfmaHalf(arc, brc, 0, 8);
            __builtin_amdgcn_sched_barrier(0);
            boundary(t);
        };
        for (int t = 0; t < NT; t += 2) {
            bodyE(t,     arA, brA, arB, brB);
            bodyE(t + 1, arB, brB, arA, brA);
        }
    } else {
        // ===== odd arm: [MFMA(t) x16 ; reads(t+1) ; MFMA(t) x16] =====
        auto bodyO = [&](int t, i32x4 (&arc)[8], i32x4 (&brc)[4],
                                i32x4 (&arn)[8], i32x4 (&brn)[4]) {
            mfmaHalf(arc, brc, 0, 4);
            __builtin_amdgcn_sched_barrier(0);
            if (t + 1 < NT) readFragsS(sn, arn, brn);
            __builtin_amdgcn_sched_barrier(0);
            mfmaHalf(arc, brc, 4, 8);
            __builtin_amdgcn_sched_barrier(0);
            boundary(t);
        };
        for (int t = 0; t < NT; t += 2) {
            bodyO(t,     arA, brA, arB, brB);
            bodyO(t + 1, arB, brB, arA, brA);
        }
    }

    // ---- epilogue: out = acc * sinv[row] + bias[col] ----
    // C/D layout (dtype-independent, m121-128): col=lane&15, row=(lane>>4)*4+reg
    int   cols[4];
    float bv[4];
    #pragma unroll
    for (int n = 0; n < 4; ++n) {
        cols[n] = (int)bcol + n * 64 + wn * 16 + l15;
        bv[n] = bias[cols[n]];
    }
    #pragma unroll
    for (int m = 0; m < 8; ++m) {
        const size_t row0 = (size_t)brow + m * 32 + wm * 16 + l4 * 4;
        float s0 = sinv[row0], s1 = sinv[row0 + 1], s2 = sinv[row0 + 2], s3 = sinv[row0 + 3];
        #pragma unroll
        for (int n = 0; n < 4; ++n) {
            out[(row0 + 0) * N_DIM + cols[n]] = (float)acc[m][n][0] * s0 + bv[n];
            out[(row0 + 1) * N_DIM + cols[n]] = (float)acc[m][n][1] * s1 + bv[n];
            out[(row0 + 2) * N_DIM + cols[n]] = (float)acc[m][n][2] * s2 + bv[n];
            out[(row0 + 3) * N_DIM + cols[n]] = (float)acc[m][n][3] * s3 + bv[n];
        }
    }
}

// ---------- fallback (only if workspace too small): correct but slow ----------

__global__ void naive_kernel(const float* __restrict__ x, const float* __restrict__ w,
                             const float* __restrict__ bias, float* __restrict__ out) {
    long long o = (long long)blockIdx.x * blockDim.x + threadIdx.x;
    if (o >= (long long)M_DIM * N_DIM) return;
    int row = (int)(o / N_DIM), col = (int)(o % N_DIM);
    float s = 0.0f;
    const float* xr = x + (size_t)row * K_DIM;
    const float* wr = w + (size_t)col * K_DIM;
    for (int k = 0; k < K_DIM; ++k) {
        float wv = wr[k];
        s += (wv > 0.0f) ? xr[k] : ((wv < 0.0f) ? -xr[k] : 0.0f);
    }
    out[o] = s + bias[col];
}

// ---------- launch ----------

extern "C" void kernel_launch(void* const* d_in, const int* in_sizes, int n_in,
                              void* d_out, int out_size, void* d_ws, size_t ws_size,
                              hipStream_t stream) {
    const float* x    = (const float*)d_in[0];
    const float* w    = (const float*)d_in[1];
    const float* bias = (const float*)d_in[2];
    float* out        = (float*)d_out;

    const size_t xq_bytes = (size_t)M_DIM * K_DIM;        // 33.6 MB
    const size_t wq_bytes = (size_t)N_DIM * K_DIM;        // 45.1 MB
    const size_t si_bytes = (size_t)M_DIM * sizeof(float);

    if (ws_size >= xq_bytes + wq_bytes + si_bytes) {
        int8_t* xq   = (int8_t*)d_ws;
        int8_t* wq   = (int8_t*)((char*)d_ws + xq_bytes);
        float*  sinv = (float*)((char*)d_ws + xq_bytes + wq_bytes);

        quant_x_kernel<<<M_DIM / 4, 256, 0, stream>>>(x, xq, sinv);
        const long long n16 = ((long long)N_DIM * K_DIM) / 16;
        sign_w_kernel<<<2048, 256, 0, stream>>>(w, wq, n16);

        const int lds_bytes = NRING * 2 * BUF;   // 163840
        hipFuncSetAttribute(reinterpret_cast<const void*>(ternary_gemm_i8),
                            hipFuncAttributeMaxDynamicSharedMemorySize, lds_bytes);
        ternary_gemm_i8<<<NWG, 512, lds_bytes, stream>>>(xq, wq, bias, sinv, out);
    } else {
        const long long total = (long long)M_DIM * N_DIM;
        naive_kernel<<<(int)((total + 255) / 256), 256, 0, stream>>>(x, w, bias, out);
    }
}

// Round 15
// 479.664 us; speedup vs baseline: 8.3966x; 1.0032x over previous
//
#include <hip/hip_runtime.h>
#include <stdint.h>

#define M_DIM 8192
#define N_DIM 11008
#define K_DIM 4096

#define BM 256
#define BN 256
#define BK 64                    // i8: 64 B per row per tile
#define NT (K_DIM / BK)          // 64 K-tiles
#define GRID_M (M_DIM / BM)      // 32
#define GRID_N (N_DIM / BN)      // 43
#define NWG (GRID_M * GRID_N)    // 1376 (divisible by 8)

#define BUF (BM * BK)            // 16384 B per tile-buffer per matrix
#define NRING 5                  // ring-5: LDS = 5*2*16384 = 163840 B (160 KiB)

typedef int i32x4 __attribute__((ext_vector_type(4)));

__device__ __forceinline__ void gload16(const int8_t* src, int8_t* dst) {
    __builtin_amdgcn_global_load_lds(
        (const __attribute__((address_space(1))) uint32_t*)src,
        (__attribute__((address_space(3))) uint32_t*)dst, 16, 0, 0);
}

// ---------- pre-pass 1: per-row (token) absmax quant of x -> i8 + inv scale ----------

__global__ __launch_bounds__(256) void quant_x_kernel(
    const float* __restrict__ x, int8_t* __restrict__ xq, float* __restrict__ sinv)
{
    const int wave = blockIdx.x * 4 + (threadIdx.x >> 6);
    const int lane = threadIdx.x & 63;
    const float* row = x + (size_t)wave * K_DIM;

    float4 v[16];
    float mx = 0.0f;
    #pragma unroll
    for (int j = 0; j < 16; ++j) {
        v[j] = *(const float4*)(row + (j * 64 + lane) * 4);
        mx = fmaxf(mx, fmaxf(fmaxf(fabsf(v[j].x), fabsf(v[j].y)),
                             fmaxf(fabsf(v[j].z), fabsf(v[j].w))));
    }
    #pragma unroll
    for (int off = 32; off > 0; off >>= 1)
        mx = fmaxf(mx, __shfl_xor(mx, off));
    if (mx < 1e-30f) mx = 1e-30f;
    const float s = 127.0f / mx;

    int8_t* orow = xq + (size_t)wave * K_DIM;
    #pragma unroll
    for (int j = 0; j < 16; ++j) {
        int a = (int)__builtin_rintf(v[j].x * s);
        int b = (int)__builtin_rintf(v[j].y * s);
        int c = (int)__builtin_rintf(v[j].z * s);
        int d = (int)__builtin_rintf(v[j].w * s);
        uint32_t p = (uint32_t)(a & 0xFF) | ((uint32_t)(b & 0xFF) << 8) |
                     ((uint32_t)(c & 0xFF) << 16) | ((uint32_t)(d & 0xFF) << 24);
        *(uint32_t*)(orow + (j * 64 + lane) * 4) = p;
    }
    if (lane == 0) sinv[wave] = mx / 127.0f;
}

// ---------- pre-pass 2: f32 w -> sign(w) in i8 (exact {-1,0,+1}) ----------

__global__ __launch_bounds__(256) void sign_w_kernel(
    const float* __restrict__ w, int8_t* __restrict__ wq, long long n16)
{
    long long i = (long long)blockIdx.x * blockDim.x + threadIdx.x;
    const long long stride = (long long)gridDim.x * blockDim.x;
    for (; i < n16; i += stride) {
        const float* src = w + i * 16;
        uint32_t pk[4];
        #pragma unroll
        for (int q = 0; q < 4; ++q) {
            float4 f = *(const float4*)(src + q * 4);
            int a = (f.x > 0.f) ? 1 : ((f.x < 0.f) ? -1 : 0);
            int b = (f.y > 0.f) ? 1 : ((f.y < 0.f) ? -1 : 0);
            int c = (f.z > 0.f) ? 1 : ((f.z < 0.f) ? -1 : 0);
            int d = (f.w > 0.f) ? 1 : ((f.w < 0.f) ? -1 : 0);
            pk[q] = (uint32_t)(a & 0xFF) | ((uint32_t)(b & 0xFF) << 8) |
                    ((uint32_t)(c & 0xFF) << 16) | ((uint32_t)(d & 0xFF) << 24);
        }
        *(i32x4*)(wq + i * 16) = (i32x4){(int)pk[0], (int)pk[1], (int)pk[2], (int)pk[3]};
    }
}

// ---------- main GEMM (i8): 256x256, BK=64, 8 waves, RING-5 LDS (160 KiB),
// ASM DS_READ + MANUAL COUNTED LGKMCNT (r14 post-mortem): five schedule
// variants (pinned/free/groups/ordered/anti-phase) ALL measured the exact
// DS+MFMA serial sum (2500 cy/tile). Uniform explanation: frag reads were
// plain C++ loads -> the COMPILER inserts the lgkm wait before each MFMA
// cluster, and (unable to disambiguate the rotated frag sets) emits a
// conservative lgkmcnt(0) that drains the just-issued next-tile reads ->
// serialization invariant to source order. This version takes wait insertion
// away from the compiler: ds_read_b128 via asm volatile ("=&v" outputs, NO
// compiler waits), and a manual lgkmcnt(12) that drains reads(t) while
// leaving reads(t+1) in flight UNDER the 32 MFMAs. Rule #18: sched_barrier(0)
// immediately after the manual lgkmcnt (hipcc hoists register-only MFMA past
// asm waits otherwise).
//
// body(t):  [12 asm ds_read frags(t+1) from slot sn]   (no waits generated)
//           lgkmcnt(12)  -> reads(t) certified; reads(t+1) stay outstanding
//           MFMA x32 on set(t)     (reads(t+1) drain underneath: ~1152 cy DS
//                                   vs ~1306 cy MFMA per CU -> hidden)
//           stage(t+4) -> slot (t-1)%5   [WAR: all waves' reads(t-1) drained
//             by their body(t-1) lgkmcnt(12), ordered by boundary(t-1) barrier]
//           vmcnt ladder (8/4/0: certifies stage(t+2) landed; never 0 until
//             tail) ; s_barrier
// Tail: t==NT-1 issues no reads -> lgkmcnt(0) drains reads(NT-1).
// RAW: reads(t+1) at body(t) need stage(t+1) landed: certified at
// boundary(t-1) vmcnt(8). All counts identical to r11 (proven, absmax 3.75).

__global__ __launch_bounds__(512, 2) void ternary_gemm_i8(
    const int8_t* __restrict__ A, const int8_t* __restrict__ B,
    const float* __restrict__ bias, const float* __restrict__ sinv,
    float* __restrict__ out)
{
    extern __shared__ int8_t lds[];
    int8_t* As = lds;                   // [NRING][BUF]
    int8_t* Bs = lds + NRING * BUF;     // [NRING][BUF]

    const int tid  = threadIdx.x;
    const int lane = tid & 63;
    const int wid  = tid >> 6;        // 0..7
    const int wm   = wid >> 2;        // 0..1
    const int wn   = wid & 3;         // 0..3
    const int l15  = lane & 15;
    const int l4   = lane >> 4;       // 0..3

    // T1: bijective XCD swizzle (NWG % 8 == 0), bn-minor for A-panel L2 reuse
    const int bid = blockIdx.x;
    const int swz = (bid & 7) * (NWG / 8) + (bid >> 3);
    const int bm  = swz / GRID_N;
    const int bn  = swz % GRID_N;
    const long brow = (long)bm * BM;
    const long bcol = (long)bn * BN;

    // ---- staging addressing (r6-verified) ----
    const int rowt = tid >> 2;                        // 0..127
    const int ssrc = (tid & 3) ^ ((tid >> 3) & 3);
    const int8_t* pA = A + (size_t)(brow + rowt) * K_DIM + ssrc * 16;
    const int8_t* pB = B + (size_t)(bcol + rowt) * K_DIM + ssrc * 16;

    auto stageAB = [&](int t, int bslot) {
        #pragma unroll
        for (int r = 0; r < 2; ++r)
            gload16(pA + (size_t)r * 128 * K_DIM + (size_t)t * BK,
                    As + bslot * BUF + r * 8192 + wid * 1024 + (lane << 4));
        #pragma unroll
        for (int r = 0; r < 2; ++r)
            gload16(pB + (size_t)r * 128 * K_DIM + (size_t)t * BK,
                    Bs + bslot * BUF + r * 8192 + wid * 1024 + (lane << 4));
    };

    // ---- fragment read addressing (r6-verified swizzle), as LDS byte addrs ----
    const int slot = l4 ^ ((l15 >> 1) & 3);
    const int aOff = (wm * 16 + l15) * 64 + slot * 16;   // + m*2048
    const int bOff = (wn * 16 + l15) * 64 + slot * 16;   // + n*4096
    const uint32_t asBase = (uint32_t)(uintptr_t)As;     // LDS offset (low 32)
    const uint32_t bsBase = (uint32_t)(uintptr_t)Bs;

    i32x4 acc[8][4];
    #pragma unroll
    for (int m = 0; m < 8; ++m)
        #pragma unroll
        for (int n = 0; n < 4; ++n) acc[m][n] = (i32x4){0, 0, 0, 0};

    i32x4 arA[8], brA[4], arB[8], brB[4];

    // 12 asm ds_read_b128: B frags first then A (order irrelevant now —
    // the manual lgkmcnt counts, not completion order).
    auto readFragsAsm = [&](int s, i32x4 (&ar)[8], i32x4 (&br)[4]) {
        const uint32_t aA = asBase + (uint32_t)(s * BUF) + (uint32_t)aOff;
        const uint32_t bA = bsBase + (uint32_t)(s * BUF) + (uint32_t)bOff;
        asm volatile("ds_read_b128 %0, %1 offset:0"     : "=&v"(br[0]) : "v"(bA));
        asm volatile("ds_read_b128 %0, %1 offset:4096"  : "=&v"(br[1]) : "v"(bA));
        asm volatile("ds_read_b128 %0, %1 offset:8192"  : "=&v"(br[2]) : "v"(bA));
        asm volatile("ds_read_b128 %0, %1 offset:12288" : "=&v"(br[3]) : "v"(bA));
        asm volatile("ds_read_b128 %0, %1 offset:0"     : "=&v"(ar[0]) : "v"(aA));
        asm volatile("ds_read_b128 %0, %1 offset:2048"  : "=&v"(ar[1]) : "v"(aA));
        asm volatile("ds_read_b128 %0, %1 offset:4096"  : "=&v"(ar[2]) : "v"(aA));
        asm volatile("ds_read_b128 %0, %1 offset:6144"  : "=&v"(ar[3]) : "v"(aA));
        asm volatile("ds_read_b128 %0, %1 offset:8192"  : "=&v"(ar[4]) : "v"(aA));
        asm volatile("ds_read_b128 %0, %1 offset:10240" : "=&v"(ar[5]) : "v"(aA));
        asm volatile("ds_read_b128 %0, %1 offset:12288" : "=&v"(ar[6]) : "v"(aA));
        asm volatile("ds_read_b128 %0, %1 offset:14336" : "=&v"(ar[7]) : "v"(aA));
    };

    // ---- prologue: stage tiles 0..3; vmcnt(8) [tiles 0,1 landed]; barrier;
    // issue asm reads(0) from slot 0 ----
    stageAB(0, 0); stageAB(1, 1); stageAB(2, 2); stageAB(3, 3);
    asm volatile("s_waitcnt vmcnt(8)" ::: "memory");
    __builtin_amdgcn_s_barrier();
    __builtin_amdgcn_sched_barrier(0);
    readFragsAsm(0, arA, brA);
    __builtin_amdgcn_sched_barrier(0);

    int sn = 1;   // ring slot of tile t+1 (reads)
    int ss = 4;   // ring slot of tile t+4 (stage)

    auto body = [&](int t, i32x4 (&arc)[8], i32x4 (&brc)[4],
                           i32x4 (&arn)[8], i32x4 (&brn)[4]) {
        const bool rd = (t + 1 < NT);

        // 1. issue next-tile frag reads (asm; no compiler waits)
        if (rd) readFragsAsm(sn, arn, brn);
        __builtin_amdgcn_sched_barrier(0);

        // 2. manual counted drain: reads(t) done, reads(t+1) stay in flight
        if (rd) { asm volatile("s_waitcnt lgkmcnt(12)" ::: "memory"); }
        else    { asm volatile("s_waitcnt lgkmcnt(0)"  ::: "memory"); }
        __builtin_amdgcn_sched_barrier(0);   // rule #18: pin MFMAs below the wait

        // 3. MFMA x32; reads(t+1) drain underneath
        __builtin_amdgcn_s_setprio(1);
        #pragma unroll
        for (int m = 0; m < 8; ++m)
            #pragma unroll
            for (int n = 0; n < 4; ++n)
                acc[m][n] = __builtin_amdgcn_mfma_i32_16x16x64_i8(arc[m], brc[n], acc[m][n], 0, 0, 0);
        __builtin_amdgcn_s_setprio(0);
        __builtin_amdgcn_sched_barrier(0);

        // 4. stage(t+4) -> slot (t-1)%5 (WAR-safe per header audit)
        if (t + 4 < NT) stageAB(t + 4, ss);
        __builtin_amdgcn_sched_barrier(0);

        // 5. boundary: vmcnt ladder + barrier (r11-proven counts)
        if (t <= NT - 5)      { asm volatile("s_waitcnt vmcnt(8)" ::: "memory"); }
        else if (t == NT - 4) { asm volatile("s_waitcnt vmcnt(4)" ::: "memory"); }
        else                  { asm volatile("s_waitcnt vmcnt(0)" ::: "memory"); }
        __builtin_amdgcn_s_barrier();
        __builtin_amdgcn_sched_barrier(0);

        sn = (sn == NRING - 1) ? 0 : sn + 1;
        ss = (ss == NRING - 1) ? 0 : ss + 1;
    };

    for (int t = 0; t < NT; t += 2) {
        body(t,     arA, brA, arB, brB);
        body(t + 1, arB, brB, arA, brA);
    }

    // ---- epilogue: out = acc * sinv[row] + bias[col] ----
    // C/D layout (dtype-independent, m121-128): col=lane&15, row=(lane>>4)*4+reg
    int   cols[4];
    float bv[4];
    #pragma unroll
    for (int n = 0; n < 4; ++n) {
        cols[n] = (int)bcol + n * 64 + wn * 16 + l15;
        bv[n] = bias[cols[n]];
    }
    #pragma unroll
    for (int m = 0; m < 8; ++m) {
        const size_t row0 = (size_t)brow + m * 32 + wm * 16 + l4 * 4;
        float s0 = sinv[row0], s1 = sinv[row0 + 1], s2 = sinv[row0 + 2], s3 = sinv[row0 + 3];
        #pragma unroll
        for (int n = 0; n < 4; ++n) {
            out[(row0 + 0) * N_DIM + cols[n]] = (float)acc[m][n][0] * s0 + bv[n];
            out[(row0 + 1) * N_DIM + cols[n]] = (float)acc[m][n][1] * s1 + bv[n];
            out[(row0 + 2) * N_DIM + cols[n]] = (float)acc[m][n][2] * s2 + bv[n];
            out[(row0 + 3) * N_DIM + cols[n]] = (float)acc[m][n][3] * s3 + bv[n];
        }
    }
}

// ---------- fallback (only if workspace too small): correct but slow ----------

__global__ void naive_kernel(const float* __restrict__ x, const float* __restrict__ w,
                             const float* __restrict__ bias, float* __restrict__ out) {
    long long o = (long long)blockIdx.x * blockDim.x + threadIdx.x;
    if (o >= (long long)M_DIM * N_DIM) return;
    int row = (int)(o / N_DIM), col = (int)(o % N_DIM);
    float s = 0.0f;
    const float* xr = x + (size_t)row * K_DIM;
    const float* wr = w + (size_t)col * K_DIM;
    for (int k = 0; k < K_DIM; ++k) {
        float wv = wr[k];
        s += (wv > 0.0f) ? xr[k] : ((wv < 0.0f) ? -xr[k] : 0.0f);
    }
    out[o] = s + bias[col];
}

// ---------- launch ----------

extern "C" void kernel_launch(void* const* d_in, const int* in_sizes, int n_in,
                              void* d_out, int out_size, void* d_ws, size_t ws_size,
                              hipStream_t stream) {
    const float* x    = (const float*)d_in[0];
    const float* w    = (const float*)d_in[1];
    const float* bias = (const float*)d_in[2];
    float* out        = (float*)d_out;

    const size_t xq_bytes = (size_t)M_DIM * K_DIM;        // 33.6 MB
    const size_t wq_bytes = (size_t)N_DIM * K_DIM;        // 45.1 MB
    const size_t si_bytes = (size_t)M_DIM * sizeof(float);

    if (ws_size >= xq_bytes + wq_bytes + si_bytes) {
        int8_t* xq   = (int8_t*)d_ws;
        int8_t* wq   = (int8_t*)((char*)d_ws + xq_bytes);
        float*  sinv = (float*)((char*)d_ws + xq_bytes + wq_bytes);

        quant_x_kernel<<<M_DIM / 4, 256, 0, stream>>>(x, xq, sinv);
        const long long n16 = ((long long)N_DIM * K_DIM) / 16;
        sign_w_kernel<<<2048, 256, 0, stream>>>(w, wq, n16);

        const int lds_bytes = NRING * 2 * BUF;   // 163840
        hipFuncSetAttribute(reinterpret_cast<const void*>(ternary_gemm_i8),
                            hipFuncAttributeMaxDynamicSharedMemorySize, lds_bytes);
        ternary_gemm_i8<<<NWG, 512, lds_bytes, stream>>>(xq, wq, bias, sinv, out);
    } else {
        const long long total = (long long)M_DIM * N_DIM;
        naive_kernel<<<(int)((total + 255) / 256), 256, 0, stream>>>(x, w, bias, out);
    }
}

// Round 16
// 463.776 us; speedup vs baseline: 8.6843x; 1.0343x over previous
//
#include <hip/hip_runtime.h>
#include <stdint.h>

#define M_DIM 8192
#define N_DIM 11008
#define K_DIM 4096

#define BM 256
#define BN 256
#define BK 64                    // i8: 64 B per row per tile
#define NT (K_DIM / BK)          // 64 K-tiles
#define GRID_M (M_DIM / BM)      // 32
#define GRID_N (N_DIM / BN)      // 43
#define NWG (GRID_M * GRID_N)    // 1376 (divisible by 8)

#define BUF (BM * BK)            // 16384 B per tile-buffer per matrix
#define NRING 4                  // ring-4: LDS = 4*2*16384 = 131072 B (128 KiB)

typedef int i32x4 __attribute__((ext_vector_type(4)));

__device__ __forceinline__ void gload16(const int8_t* src, int8_t* dst) {
    __builtin_amdgcn_global_load_lds(
        (const __attribute__((address_space(1))) uint32_t*)src,
        (__attribute__((address_space(3))) uint32_t*)dst, 16, 0, 0);
}

// ---------- pre-pass 1: per-row (token) absmax quant of x -> i8 + inv scale ----------

__global__ __launch_bounds__(256) void quant_x_kernel(
    const float* __restrict__ x, int8_t* __restrict__ xq, float* __restrict__ sinv)
{
    const int wave = blockIdx.x * 4 + (threadIdx.x >> 6);
    const int lane = threadIdx.x & 63;
    const float* row = x + (size_t)wave * K_DIM;

    float4 v[16];
    float mx = 0.0f;
    #pragma unroll
    for (int j = 0; j < 16; ++j) {
        v[j] = *(const float4*)(row + (j * 64 + lane) * 4);
        mx = fmaxf(mx, fmaxf(fmaxf(fabsf(v[j].x), fabsf(v[j].y)),
                             fmaxf(fabsf(v[j].z), fabsf(v[j].w))));
    }
    #pragma unroll
    for (int off = 32; off > 0; off >>= 1)
        mx = fmaxf(mx, __shfl_xor(mx, off));
    if (mx < 1e-30f) mx = 1e-30f;
    const float s = 127.0f / mx;

    int8_t* orow = xq + (size_t)wave * K_DIM;
    #pragma unroll
    for (int j = 0; j < 16; ++j) {
        int a = (int)__builtin_rintf(v[j].x * s);
        int b = (int)__builtin_rintf(v[j].y * s);
        int c = (int)__builtin_rintf(v[j].z * s);
        int d = (int)__builtin_rintf(v[j].w * s);
        uint32_t p = (uint32_t)(a & 0xFF) | ((uint32_t)(b & 0xFF) << 8) |
                     ((uint32_t)(c & 0xFF) << 16) | ((uint32_t)(d & 0xFF) << 24);
        *(uint32_t*)(orow + (j * 64 + lane) * 4) = p;
    }
    if (lane == 0) sinv[wave] = mx / 127.0f;
}

// ---------- pre-pass 2: f32 w -> sign(w) in i8 (exact {-1,0,+1}) ----------

__global__ __launch_bounds__(256) void sign_w_kernel(
    const float* __restrict__ w, int8_t* __restrict__ wq, long long n16)
{
    long long i = (long long)blockIdx.x * blockDim.x + threadIdx.x;
    const long long stride = (long long)gridDim.x * blockDim.x;
    for (; i < n16; i += stride) {
        const float* src = w + i * 16;
        uint32_t pk[4];
        #pragma unroll
        for (int q = 0; q < 4; ++q) {
            float4 f = *(const float4*)(src + q * 4);
            int a = (f.x > 0.f) ? 1 : ((f.x < 0.f) ? -1 : 0);
            int b = (f.y > 0.f) ? 1 : ((f.y < 0.f) ? -1 : 0);
            int c = (f.z > 0.f) ? 1 : ((f.z < 0.f) ? -1 : 0);
            int d = (f.w > 0.f) ? 1 : ((f.w < 0.f) ? -1 : 0);
            pk[q] = (uint32_t)(a & 0xFF) | ((uint32_t)(b & 0xFF) << 8) |
                    ((uint32_t)(c & 0xFF) << 16) | ((uint32_t)(d & 0xFF) << 24);
        }
        *(i32x4*)(wq + i * 16) = (i32x4){(int)pk[0], (int)pk[1], (int)pk[2], (int)pk[3]};
    }
}

// ---------- main GEMM (i8): 256x256, BK=64, 16 WAVES (1024 thr), RING-4.
// r15 post-mortem: six schedule variants (incl. manual asm waits) all hit the
// DS+MFMA serial sum at 2 waves/SIMD — both resident waves phase-align, no
// third wave fills the idle pipe. Root cause: acc[8][4]=128 AGPR + 124 VGPR
// = 252 regs -> 2 waves/SIMD (VRF=512/SIMD, m69). THIS kernel: 16 waves x
// 64x64 output (acc[4][4]=64 AGPR, single frag set 32 VGPR, ~120 total,
// launch_bounds(1024,4) caps at 128) -> 4 waves/SIMD. TLP does the overlap:
// wave k's 16-MFMA burst (~326 cy) covers waves k+1..k+3's DS reads.
//
// Ring-4, NO mid-body barrier: stage(t+3) at body(t) -> slot (t+3)%4 =
// (t-1)%4, whose readers (all waves' reads(t-1)) completed before their
// MFMA(t-1) (operand dependence) which precedes boundary(t-1)'s barrier.
// body(t): 8 ds_reads frags(t) [compiler lgkm before MFMA]; stage(t+3);
//          16 MFMA; vmcnt ladder; s_barrier.
// vmcnt ladder (2-inst stages): at boundary(t) outstanding (oldest first)
// st(t+1),st(t+2),st(t+3) = 6 -> vmcnt(4) drains st(t+1) (tile t+1 certified
// for next body). t==NT-3 (no st issued): {st(t+1),st(t+2)} -> vmcnt(2);
// t>=NT-2: vmcnt(0). Prologue: stage 0,1,2 (6 insts); vmcnt(4) -> tile 0.
// RAW st(t)->reads(t): drained at boundary(t-1) vmcnt(4)+barrier. All
// swizzle/layout formulas identical to r6-verified (row-dependence re-checked
// for wr*64/f*16 terms: drops out of (row>>1)&3).

__global__ __launch_bounds__(1024, 4) void ternary_gemm_i8(
    const int8_t* __restrict__ A, const int8_t* __restrict__ B,
    const float* __restrict__ bias, const float* __restrict__ sinv,
    float* __restrict__ out)
{
    extern __shared__ int8_t lds[];
    int8_t* As = lds;                   // [NRING][BUF]
    int8_t* Bs = lds + NRING * BUF;     // [NRING][BUF]

    const int tid  = threadIdx.x;
    const int lane = tid & 63;
    const int wid  = tid >> 6;        // 0..15
    const int wr   = wid >> 2;        // 0..3  (64-row slab)
    const int wc   = wid & 3;         // 0..3  (64-col slab)
    const int l15  = lane & 15;
    const int l4   = lane >> 4;       // 0..3

    // T1: bijective XCD swizzle (NWG % 8 == 0), bn-minor for A-panel L2 reuse
    const int bid = blockIdx.x;
    const int swz = (bid & 7) * (NWG / 8) + (bid >> 3);
    const int bm  = swz / GRID_N;
    const int bn  = swz % GRID_N;
    const long brow = (long)bm * BM;
    const long bcol = (long)bn * BN;

    // ---- staging addressing: 1024 threads cover 256 rows x 4 slots;
    // row = tid>>2, LDS dest linear (tid*16), global src slot inverse-swizzled
    // ssrc = (tid&3) ^ ((row>>1)&3) = (tid&3) ^ ((tid>>3)&3) ----
    const int rowt = tid >> 2;                        // 0..255
    const int ssrc = (tid & 3) ^ ((tid >> 3) & 3);
    const int8_t* pA = A + (size_t)(brow + rowt) * K_DIM + ssrc * 16;
    const int8_t* pB = B + (size_t)(bcol + rowt) * K_DIM + ssrc * 16;

    auto stageAB = [&](int t, int bslot) {
        gload16(pA + (size_t)t * BK, As + bslot * BUF + tid * 16);
        gload16(pB + (size_t)t * BK, Bs + bslot * BUF + tid * 16);
    };

    // ---- fragment read addressing (r6-verified swizzle) ----
    const int slot = l4 ^ ((l15 >> 1) & 3);
    const int aOff = (wr * 64 + l15) * 64 + slot * 16;   // + m*1024 (m*16 rows)
    const int bOff = (wc * 64 + l15) * 64 + slot * 16;   // + n*1024

    i32x4 acc[4][4];
    #pragma unroll
    for (int m = 0; m < 4; ++m)
        #pragma unroll
        for (int n = 0; n < 4; ++n) acc[m][n] = (i32x4){0, 0, 0, 0};

    // ---- prologue: stage tiles 0,1,2; vmcnt(4) [tile 0 landed]; barrier ----
    stageAB(0, 0); stageAB(1, 1); stageAB(2, 2);
    asm volatile("s_waitcnt vmcnt(4)" ::: "memory");
    __builtin_amdgcn_s_barrier();
    __builtin_amdgcn_sched_barrier(0);

    for (int t = 0; t < NT; ++t) {
        const int b = t & 3;

        // 8 frag reads for THIS tile (compiler inserts lgkm before MFMA use;
        // at 4 waves/SIMD the wait is covered by other waves' MFMA bursts)
        i32x4 ar[4], br[4];
        #pragma unroll
        for (int m = 0; m < 4; ++m)
            ar[m] = *(const i32x4*)(As + b * BUF + m * 1024 + aOff);
        #pragma unroll
        for (int n = 0; n < 4; ++n)
            br[n] = *(const i32x4*)(Bs + b * BUF + n * 1024 + bOff);

        // stage(t+3) -> slot (t-1)%4 (WAR-safe: readers done pre-boundary(t-1))
        if (t + 3 < NT) stageAB(t + 3, (t + 3) & 3);

        __builtin_amdgcn_s_setprio(1);
        #pragma unroll
        for (int m = 0; m < 4; ++m)
            #pragma unroll
            for (int n = 0; n < 4; ++n)
                acc[m][n] = __builtin_amdgcn_mfma_i32_16x16x64_i8(ar[m], br[n], acc[m][n], 0, 0, 0);
        __builtin_amdgcn_s_setprio(0);
        __builtin_amdgcn_sched_barrier(0);

        // boundary: vmcnt ladder (certify tile t+1) + barrier
        if (t <= NT - 4)      { asm volatile("s_waitcnt vmcnt(4)" ::: "memory"); }
        else if (t == NT - 3) { asm volatile("s_waitcnt vmcnt(2)" ::: "memory"); }
        else                  { asm volatile("s_waitcnt vmcnt(0)" ::: "memory"); }
        __builtin_amdgcn_s_barrier();
        __builtin_amdgcn_sched_barrier(0);
    }

    // ---- epilogue: out = acc * sinv[row] + bias[col] ----
    // C/D layout (dtype-independent, m121-128): col=lane&15, row=(lane>>4)*4+reg
    int   cols[4];
    float bv[4];
    #pragma unroll
    for (int n = 0; n < 4; ++n) {
        cols[n] = (int)bcol + wc * 64 + n * 16 + l15;
        bv[n] = bias[cols[n]];
    }
    #pragma unroll
    for (int m = 0; m < 4; ++m) {
        const size_t row0 = (size_t)brow + wr * 64 + m * 16 + l4 * 4;
        float s0 = sinv[row0], s1 = sinv[row0 + 1], s2 = sinv[row0 + 2], s3 = sinv[row0 + 3];
        #pragma unroll
        for (int n = 0; n < 4; ++n) {
            out[(row0 + 0) * N_DIM + cols[n]] = (float)acc[m][n][0] * s0 + bv[n];
            out[(row0 + 1) * N_DIM + cols[n]] = (float)acc[m][n][1] * s1 + bv[n];
            out[(row0 + 2) * N_DIM + cols[n]] = (float)acc[m][n][2] * s2 + bv[n];
            out[(row0 + 3) * N_DIM + cols[n]] = (float)acc[m][n][3] * s3 + bv[n];
        }
    }
}

// ---------- fallback (only if workspace too small): correct but slow ----------

__global__ void naive_kernel(const float* __restrict__ x, const float* __restrict__ w,
                             const float* __restrict__ bias, float* __restrict__ out) {
    long long o = (long long)blockIdx.x * blockDim.x + threadIdx.x;
    if (o >= (long long)M_DIM * N_DIM) return;
    int row = (int)(o / N_DIM), col = (int)(o % N_DIM);
    float s = 0.0f;
    const float* xr = x + (size_t)row * K_DIM;
    const float* wr = w + (size_t)col * K_DIM;
    for (int k = 0; k < K_DIM; ++k) {
        float wv = wr[k];
        s += (wv > 0.0f) ? xr[k] : ((wv < 0.0f) ? -xr[k] : 0.0f);
    }
    out[o] = s + bias[col];
}

// ---------- launch ----------

extern "C" void kernel_launch(void* const* d_in, const int* in_sizes, int n_in,
                              void* d_out, int out_size, void* d_ws, size_t ws_size,
                              hipStream_t stream) {
    const float* x    = (const float*)d_in[0];
    const float* w    = (const float*)d_in[1];
    const float* bias = (const float*)d_in[2];
    float* out        = (float*)d_out;

    const size_t xq_bytes = (size_t)M_DIM * K_DIM;        // 33.6 MB
    const size_t wq_bytes = (size_t)N_DIM * K_DIM;        // 45.1 MB
    const size_t si_bytes = (size_t)M_DIM * sizeof(float);

    if (ws_size >= xq_bytes + wq_bytes + si_bytes) {
        int8_t* xq   = (int8_t*)d_ws;
        int8_t* wq   = (int8_t*)((char*)d_ws + xq_bytes);
        float*  sinv = (float*)((char*)d_ws + xq_bytes + wq_bytes);

        quant_x_kernel<<<M_DIM / 4, 256, 0, stream>>>(x, xq, sinv);
        const long long n16 = ((long long)N_DIM * K_DIM) / 16;
        sign_w_kernel<<<2048, 256, 0, stream>>>(w, wq, n16);

        const int lds_bytes = NRING * 2 * BUF;   // 131072
        hipFuncSetAttribute(reinterpret_cast<const void*>(ternary_gemm_i8),
                            hipFuncAttributeMaxDynamicSharedMemorySize, lds_bytes);
        ternary_gemm_i8<<<NWG, 1024, lds_bytes, stream>>>(xq, wq, bias, sinv, out);
    } else {
        const long long total = (long long)M_DIM * N_DIM;
        naive_kernel<<<(int)((total + 255) / 256), 256, 0, stream>>>(x, w, bias, out);
    }
}